// Round 2
// baseline (2605.797 us; speedup 1.0000x reference)
//
#include <hip/hip_runtime.h>

// ---------------------------------------------------------------------------
// LSTM autoencoder w/ attention, MI355X fp16-MFMA implementation.
// S=128, B=256, IN=H=OUT=1024.  All GEMMs plain fp16 inputs, fp32 accumulate.
// R1 fix: k_step A-tile staging was missing the m0 block offset (batch rows
// 64..255 were computed from rows 0..63). One-line address fix.
// ---------------------------------------------------------------------------

typedef _Float16 half8 __attribute__((ext_vector_type(8)));
typedef float f32x4 __attribute__((ext_vector_type(4)));

#define S_  128
#define B_  256
#define HDIM 1024
#define BH  262144          // B*H
#define K2  2048            // IN + H

// async global -> LDS, 16B per lane, wave-uniform LDS base
__device__ __forceinline__ void g2l16(void* lds_base, const void* g) {
  __builtin_amdgcn_global_load_lds(
      (const __attribute__((address_space(1))) void*)g,
      (__attribute__((address_space(3))) void*)lds_base, 16, 0, 0);
}

__device__ __forceinline__ float sigmoidf_(float x) {
  return 1.f / (1.f + __expf(-x));
}
__device__ __forceinline__ float tanhf_(float x) {
  float e = __expf(-2.f * fabsf(x));
  float t = (1.f - e) / (1.f + e);
  return x < 0.f ? -t : t;
}

// --------------------------- converters ------------------------------------
__global__ __launch_bounds__(256) void k_cvt(const float* __restrict__ src,
                                             _Float16* __restrict__ dst) {
  size_t i = ((size_t)blockIdx.x * 256 + threadIdx.x) * 8;
  float4 u = *(const float4*)(src + i);
  float4 v = *(const float4*)(src + i + 4);
  half8 h;
  h[0] = u.x; h[1] = u.y; h[2] = u.z; h[3] = u.w;
  h[4] = v.x; h[5] = v.y; h[6] = v.z; h[7] = v.w;
  *(half8*)(dst + i) = h;
}

// Wcat[r][k] = k<1024 ? W_ih[r][k] : W_hh[r][k-1024]   (fp16, [4096][2048])
__global__ __launch_bounds__(256) void k_wcat(const float* __restrict__ Wih,
                                              const float* __restrict__ Whh,
                                              _Float16* __restrict__ Wc) {
  size_t i = ((size_t)blockIdx.x * 256 + threadIdx.x) * 8;
  int r = (int)(i >> 11), k = (int)(i & 2047);
  const float* src = (k < 1024) ? (Wih + (size_t)r * 1024 + k)
                                : (Whh + (size_t)r * 1024 + (k - 1024));
  float4 u = *(const float4*)(src);
  float4 v = *(const float4*)(src + 4);
  half8 h;
  h[0] = u.x; h[1] = u.y; h[2] = u.z; h[3] = u.w;
  h[4] = v.x; h[5] = v.y; h[6] = v.z; h[7] = v.w;
  *(half8*)(Wc + i) = h;
}

// cbuf = c0 ; hs[0] = fp16(h0) ; bias = b_ih + b_hh
__global__ __launch_bounds__(256) void k_init(const float* __restrict__ h0,
                                              const float* __restrict__ c0,
                                              const float* __restrict__ bih,
                                              const float* __restrict__ bhh,
                                              _Float16* __restrict__ hs0,
                                              float* __restrict__ cbuf,
                                              float* __restrict__ bias) {
  int i = blockIdx.x * 256 + threadIdx.x;   // 262144 total
  cbuf[i] = c0[i];
  hs0[i] = (_Float16)h0[i];
  if (i < 4096) bias[i] = bih[i] + bhh[i];
}

// row softmax of attnW [128][128] -> fp32 A
__global__ __launch_bounds__(64) void k_softmax(const float* __restrict__ W,
                                                float* __restrict__ A) {
  int r = blockIdx.x, lane = threadIdx.x;
  float v0 = W[r * 128 + lane], v1 = W[r * 128 + 64 + lane];
  float m = fmaxf(v0, v1);
  for (int off = 32; off; off >>= 1) m = fmaxf(m, __shfl_xor(m, off));
  float e0 = __expf(v0 - m), e1 = __expf(v1 - m);
  float s = e0 + e1;
  for (int off = 32; off; off >>= 1) s += __shfl_xor(s, off);
  float inv = 1.f / s;
  A[r * 128 + lane] = e0 * inv;
  A[r * 128 + 64 + lane] = e1 * inv;
}

// --------------------------- fused LSTM step --------------------------------
// gates[B,4H] = [x_t | h_{t-1}] @ Wcat^T + bias, then cell, h -> hs[t+1].
// Block: 64 batch-rows x 16 H-cols x 4 gates. Grid 256 (n-tile-major).
// BK=128, double-buffered LDS (A 16KB + B 16KB per buffer = 64KB total).
__global__ __launch_bounds__(256) void k_step(const _Float16* __restrict__ Xh,
                                              const _Float16* __restrict__ Wc,
                                              const float* __restrict__ bias,
                                              _Float16* __restrict__ hs,
                                              float* __restrict__ cbuf,
                                              int t) {
  __shared__ char smem[65536];
  const int tid = threadIdx.x;
  const int wave = tid >> 6;
  const int lane = tid & 63;
  const int n_tile = blockIdx.x & 63;   // consecutive bids -> consecutive n (XCD-stable W)
  const int m_tile = blockIdx.x >> 6;
  const int n0 = n_tile * 16;
  const int m0 = m_tile * 64;

  const _Float16* Xt = Xh + (size_t)t * BH;       // x_t rows, stride 1024
  const _Float16* Hp = hs + (size_t)t * BH;       // h_{t-1} rows, stride 1024

  f32x4 acc[4];
  #pragma unroll
  for (int g = 0; g < 4; ++g) acc[g] = (f32x4){0.f, 0.f, 0.f, 0.f};

  // stage one BK=128 tile pair into buffer p.  2048 16B-chunks, 8 per thread.
  // LDS row = 256B = 16 chunks, XOR swizzle chunk c -> c ^ (row & 15).
  auto stage = [&](int p, int k0) {
    const _Float16* Ab = (k0 < 1024) ? (Xt + k0) : (Hp + (k0 - 1024));
    char* base = smem + p * 32768;
    #pragma unroll
    for (int q = 0; q < 8; ++q) {
      int grp = q * 4 + wave;                 // 0..31, wave-uniform
      char* dst = base + grp * 1024;          // + lane*16 done by HW
      int s = grp * 64 + lane;
      if (s < 1024) {                         // A tile: 64 rows x 16 chunks
        int r = s >> 4, c = s & 15;
        int kc = c ^ (r & 15);
        g2l16(dst, Ab + (size_t)(m0 + r) * 1024 + kc * 8);   // R1 FIX: + m0
      } else {                                // B tile: 4 gate strips x 16 rows
        int sb = s - 1024;
        int r = sb >> 4, c = sb & 15;
        int kc = c ^ (r & 15);
        int row = (r >> 4) * 1024 + n0 + (r & 15);
        g2l16(dst, Wc + (size_t)row * 2048 + k0 + kc * 8);
      }
    }
  };

  stage(0, 0);
  for (int iter = 0; iter < 16; ++iter) {
    int p = iter & 1;
    __syncthreads();                          // drains stage(p); prefetch not yet issued
    if (iter + 1 < 16) stage(1 - p, (iter + 1) * 128);   // flies during compute
    const char* At = smem + p * 32768;
    const char* Bt = At + 16384;
    #pragma unroll
    for (int k32 = 0; k32 < 4; ++k32) {
      int kc = k32 * 4 + (lane >> 4);
      int ra = wave * 16 + (lane & 15);
      half8 a = *(const half8*)(At + ra * 256 + ((kc ^ (ra & 15)) * 16));
      #pragma unroll
      for (int g = 0; g < 4; ++g) {
        int rb = g * 16 + (lane & 15);
        half8 b = *(const half8*)(Bt + rb * 256 + ((kc ^ (rb & 15)) * 16));
        acc[g] = __builtin_amdgcn_mfma_f32_16x16x32_f16(a, b, acc[g], 0, 0, 0);
      }
    }
  }

  // epilogue: lane owns 4 (m,n) positions with all 4 gates in-register.
  // C layout: col = lane&15, row = (lane>>4)*4 + reg.
  int n = n0 + (lane & 15);
  float bi = bias[n], bf = bias[1024 + n], bg = bias[2048 + n], bo = bias[3072 + n];
  int mrow0 = m0 + wave * 16 + (lane >> 4) * 4;
  _Float16* hnext = hs + (size_t)(t + 1) * BH;
  #pragma unroll
  for (int r = 0; r < 4; ++r) {
    size_t idx = (size_t)(mrow0 + r) * 1024 + n;
    float gi = sigmoidf_(acc[0][r] + bi);
    float gf = sigmoidf_(acc[1][r] + bf);
    float gg = tanhf_(acc[2][r] + bg);
    float go = sigmoidf_(acc[3][r] + bo);
    float c = gf * cbuf[idx] + gi * gg;
    cbuf[idx] = c;
    hnext[idx] = (_Float16)(go * tanhf_(c));
  }
}

// --------------------------- attention mix ----------------------------------
// att[x, c] = sum_y A[x,y] * hs[y+1, c]   (VALU fp32, A-block in LDS)
__global__ __launch_bounds__(256) void k_attn(const float* __restrict__ Asm,
                                              const _Float16* __restrict__ hs,
                                              _Float16* __restrict__ att) {
  __shared__ float lA[32 * 128];
  const int tid = threadIdx.x;
  const int x0 = blockIdx.y * 32;
  const size_t c = (size_t)blockIdx.x * 256 + tid;
  for (int s = tid; s < 4096; s += 256)
    lA[s] = Asm[(x0 + (s >> 7)) * 128 + (s & 127)];
  __syncthreads();
  float acc[32];
  #pragma unroll
  for (int j = 0; j < 32; ++j) acc[j] = 0.f;
  #pragma unroll 8
  for (int y = 0; y < 128; ++y) {
    float hv = (float)hs[(size_t)(y + 1) * BH + c];
    #pragma unroll
    for (int j = 0; j < 32; ++j) acc[j] += lA[j * 128 + y] * hv;
  }
  #pragma unroll
  for (int j = 0; j < 32; ++j)
    att[(size_t)(x0 + j) * BH + c] = (_Float16)acc[j];
}

// --------------------------- final linear -----------------------------------
// out[32768,1024] = att @ linW^T + linb.  128x128 tile, BK=64, dbuf LDS.
__global__ __launch_bounds__(256) void k_final(const _Float16* __restrict__ att,
                                               const _Float16* __restrict__ Wl,
                                               const float* __restrict__ bvec,
                                               float* __restrict__ out) {
  __shared__ char smem[65536];
  const int tid = threadIdx.x, wave = tid >> 6, lane = tid & 63;
  const int m0 = (blockIdx.x >> 3) * 128;
  const int n0 = (blockIdx.x & 7) * 128;
  const int mh = (wave & 1) * 64, nh = (wave >> 1) * 64;

  f32x4 acc[4][4];
  #pragma unroll
  for (int i = 0; i < 4; ++i)
    #pragma unroll
    for (int j = 0; j < 4; ++j) acc[i][j] = (f32x4){0.f, 0.f, 0.f, 0.f};

  // LDS row = 128B = 8 chunks, swizzle c ^ (row & 7)
  auto stage = [&](int p, int k0) {
    char* base = smem + p * 32768;
    #pragma unroll
    for (int q = 0; q < 8; ++q) {
      int grp = q * 4 + wave;
      char* dst = base + grp * 1024;
      int s = grp * 64 + lane;
      if (s < 1024) {                      // A: 128 rows x 8 chunks
        int r = s >> 3, c = s & 7;
        int kc = c ^ (r & 7);
        g2l16(dst, att + (size_t)(m0 + r) * 1024 + k0 + kc * 8);
      } else {                             // B: 128 rows x 8 chunks
        int sb = s - 1024;
        int r = sb >> 3, c = sb & 7;
        int kc = c ^ (r & 7);
        g2l16(dst, Wl + (size_t)(n0 + r) * 1024 + k0 + kc * 8);
      }
    }
  };

  stage(0, 0);
  for (int iter = 0; iter < 16; ++iter) {
    int p = iter & 1;
    __syncthreads();
    if (iter + 1 < 16) stage(1 - p, (iter + 1) * 64);
    const char* At = smem + p * 32768;
    const char* Bt = At + 16384;
    #pragma unroll
    for (int k32 = 0; k32 < 2; ++k32) {
      int kc = k32 * 4 + (lane >> 4);      // 0..7
      half8 a[4], b[4];
      #pragma unroll
      for (int i = 0; i < 4; ++i) {
        int ra = mh + i * 16 + (lane & 15);
        a[i] = *(const half8*)(At + ra * 128 + ((kc ^ (ra & 7)) * 16));
        int rb = nh + i * 16 + (lane & 15);
        b[i] = *(const half8*)(Bt + rb * 128 + ((kc ^ (rb & 7)) * 16));
      }
      #pragma unroll
      for (int i = 0; i < 4; ++i)
        #pragma unroll
        for (int j = 0; j < 4; ++j)
          acc[i][j] = __builtin_amdgcn_mfma_f32_16x16x32_f16(a[i], b[j], acc[i][j], 0, 0, 0);
    }
  }

  #pragma unroll
  for (int i = 0; i < 4; ++i) {
    int m = m0 + mh + i * 16 + (lane >> 4) * 4;
    #pragma unroll
    for (int j = 0; j < 4; ++j) {
      int n = n0 + nh + j * 16 + (lane & 15);
      float bv = bvec[n];
      #pragma unroll
      for (int r = 0; r < 4; ++r)
        out[(size_t)(m + r) * 1024 + n] = acc[i][j][r] + bv;
    }
  }
}

// --------------------------- launch -----------------------------------------
extern "C" void kernel_launch(void* const* d_in, const int* in_sizes, int n_in,
                              void* d_out, int out_size, void* d_ws, size_t ws_size,
                              hipStream_t stream) {
  const float* X     = (const float*)d_in[0];
  const float* h0    = (const float*)d_in[1];
  const float* c0    = (const float*)d_in[2];
  const float* Wih   = (const float*)d_in[3];
  const float* Whh   = (const float*)d_in[4];
  const float* bih   = (const float*)d_in[5];
  const float* bhh   = (const float*)d_in[6];
  const float* attnW = (const float*)d_in[7];
  const float* linW  = (const float*)d_in[8];
  const float* linb  = (const float*)d_in[9];
  float* out = (float*)d_out;
  char* ws = (char*)d_ws;

  // workspace layout (bytes), ~212 MB total
  _Float16* Xh  = (_Float16*)(ws + 0);           // 67,108,864
  _Float16* Wc  = (_Float16*)(ws + 67108864);    // 16,777,216
  _Float16* Wl  = (_Float16*)(ws + 83886080);    //  2,097,152
  _Float16* hs  = (_Float16*)(ws + 85983232);    // 129 slots * 524,288
  _Float16* att = (_Float16*)(ws + 153616384);   // 67,108,864
  float* cbuf   = (float*)(ws + 220725248);      //  1,048,576
  float* bias   = (float*)(ws + 221773824);      //     16,384
  float* Asm    = (float*)(ws + 221790208);      //     65,536

  k_cvt<<<16384, 256, 0, stream>>>(X, Xh);
  k_wcat<<<4096, 256, 0, stream>>>(Wih, Whh, Wc);
  k_cvt<<<512, 256, 0, stream>>>(linW, Wl);
  k_init<<<1024, 256, 0, stream>>>(h0, c0, bih, bhh, hs, cbuf, bias);
  k_softmax<<<128, 64, 0, stream>>>(attnW, Asm);

  for (int t = 0; t < S_; ++t)
    k_step<<<256, 256, 0, stream>>>(Xh, Wc, bias, hs, cbuf, t);

  k_attn<<<dim3(1024, 4), 256, 0, stream>>>(Asm, hs, att);
  k_final<<<2048, 256, 0, stream>>>(att, Wl, linb, out);
}